// Round 14
// baseline (489.015 us; speedup 1.0000x reference)
//
#include <hip/hip_runtime.h>

#define N_EDGE 262144
#define N_TRI  1048576
#define DIM    128
#define NRBF   6
#define ADIM   49
#define NBIL   8
#define TE     64
#define TP     2      // tiles per block
#define NTHR   256
#define SXD    68     // activation LDS row stride in dwords (272 B)
#define EB2    2048
#define NSL    4

typedef __attribute__((ext_vector_type(8))) short bf16x8;
typedef __attribute__((ext_vector_type(4))) float f32x4;

__device__ __forceinline__ float fast_rcp(float x) {
    float r; asm("v_rcp_f32 %0, %1" : "=v"(r) : "v"(x)); return r;
}
__device__ __forceinline__ float fast_exp2(float x) {
    float r; asm("v_exp_f32 %0, %1" : "=v"(r) : "v"(x)); return r;
}
__device__ __forceinline__ float silu_f(float x) {
    return x * fast_rcp(1.f + fast_exp2(-1.44269504f * x));
}
__device__ __forceinline__ unsigned short f2bf(float f) {
    unsigned int u = __float_as_uint(f);
    return (unsigned short)((u + 0x7FFFu + ((u >> 16) & 1u)) >> 16);
}
__device__ __forceinline__ unsigned int pk2(float x, float y) {
    unsigned int r;
    asm("v_cvt_pk_bf16_f32 %0, %1, %2" : "=v"(r) : "v"(x), "v"(y));
    return r;
}
__device__ __forceinline__ float bf2f(unsigned short u) {
    return __uint_as_float(((unsigned int)u) << 16);
}

// ---------------------------------------------------------------------------
// prep: weights -> bf16 [n][k_stored], k-permuted to match packed activations.
// ---------------------------------------------------------------------------
__global__ __launch_bounds__(256) void prep_w_k(
    const float* __restrict__ nbr, const float* __restrict__ mji,
    const float* __restrict__ post, const float* __restrict__ res,
    const float* __restrict__ fw, unsigned short* __restrict__ wt)
{
    int idx = blockIdx.x * 256 + threadIdx.x;          // 278528 total
    if (idx < 9 * 16384) {
        int m = idx >> 14, rr = idx & 16383;
        int n = rr >> 7, ks = rr & 127;
        int ko = (ks & ~31) | ((ks & 1) << 4) | ((ks >> 1) & 15);
        const float* src = (m == 0) ? nbr : (m == 1) ? mji : (m == 2) ? post
                          : (res + (size_t)(m - 3) * 16384);
        wt[idx] = f2bf(src[ko * DIM + n]);
    } else {
        int r2 = idx - 9 * 16384;
        int n = r2 >> 10, j = (r2 >> 7) & 7, ls = r2 & 127;
        int lo = (ls & ~31) | ((ls & 1) << 4) | ((ls >> 1) & 15);
        wt[idx] = f2bf(fw[(size_t)(n * NBIL + j) * DIM + lo]);
    }
}

// ---------------------------------------------------------------------------
__global__ __launch_bounds__(256) void ta_all_k(
    const float* __restrict__ a_sbf, const float* __restrict__ a_sbf_w,
    float* __restrict__ taw)
{
    __shared__ __align__(16) float sA[256 * ADIM];
    __shared__ float sWa[ADIM * NBIL];
    const int tid = threadIdx.x;
    const size_t w0 = (size_t)blockIdx.x * 256;

    {
        const float4* src = (const float4*)(a_sbf + w0 * ADIM);
        float4* dst = (float4*)sA;
        for (int i = tid; i < (256 * ADIM) / 4; i += 256) dst[i] = src[i];
    }
    for (int i = tid; i < ADIM * NBIL; i += 256) sWa[i] = a_sbf_w[i];
    __syncthreads();

    float ta[NBIL];
    #pragma unroll
    for (int j = 0; j < NBIL; ++j) ta[j] = 0.0f;
    const float* row = sA + tid * ADIM;
    #pragma unroll
    for (int k = 0; k < ADIM; ++k) {
        float v = row[k];
        #pragma unroll
        for (int j = 0; j < NBIL; ++j) ta[j] = fmaf(v, sWa[k * NBIL + j], ta[j]);
    }
    float4* dst = (float4*)(taw + (w0 + tid) * NBIL);
    dst[0] = make_float4(ta[0], ta[1], ta[2], ta[3]);
    dst[1] = make_float4(ta[4], ta[5], ta[6], ta[7]);
}

// ---------------------------------------------------------------------------
__global__ __launch_bounds__(1024) void seg_reduce_k(
    const float* __restrict__ taw, const int* __restrict__ kj_idx,
    float* __restrict__ ta_sum)
{
    __shared__ float acc[EB2 * NBIL];                  // 64 KB
    const int tid = threadIdx.x;
    const int eg = blockIdx.x >> 2;
    const int sl = blockIdx.x & 3;
    const int lo = eg * EB2;

    for (int i = tid; i < EB2 * NBIL; i += 1024) acc[i] = 0.f;
    __syncthreads();

    const int4* kj4 = (const int4*)kj_idx;
    const int i0 = sl * (N_TRI / 4 / NSL);
    const int i1 = i0 + (N_TRI / 4 / NSL);
    for (int i = i0 + tid; i < i1; i += 1024) {
        int4 v = kj4[i];
        int w0 = i * 4;
        #pragma unroll
        for (int k = 0; k < 4; ++k) {
            int e = (k == 0) ? v.x : (k == 1) ? v.y : (k == 2) ? v.z : v.w;
            unsigned d = (unsigned)(e - lo);
            if (d < (unsigned)EB2) {
                const float4* p = (const float4*)(taw + (size_t)(w0 + k) * NBIL);
                float4 a = p[0], b = p[1];
                float* q = acc + d * NBIL;
                atomicAdd(q + 0, a.x); atomicAdd(q + 1, a.y);
                atomicAdd(q + 2, a.z); atomicAdd(q + 3, a.w);
                atomicAdd(q + 4, b.x); atomicAdd(q + 5, b.y);
                atomicAdd(q + 6, b.z); atomicAdd(q + 7, b.w);
            }
        }
    }
    __syncthreads();
    for (int i = tid; i < EB2 * NBIL; i += 1024)
        unsafeAtomicAdd(ta_sum + (size_t)lo * NBIL + i, acc[i]);
}

// ---------------------------------------------------------------------------
__global__ __launch_bounds__(256) void triplet_atomic_k(
    const float* __restrict__ a_sbf, const float* __restrict__ a_sbf_w,
    const int* __restrict__ kj_idx, float* __restrict__ ta_sum)
{
    __shared__ __align__(16) float sA[256 * ADIM];
    __shared__ float sWa[ADIM * NBIL];
    const int tid = threadIdx.x;
    const size_t w0 = (size_t)blockIdx.x * 256;
    {
        const float4* src = (const float4*)(a_sbf + w0 * ADIM);
        float4* dst = (float4*)sA;
        for (int i = tid; i < (256 * ADIM) / 4; i += 256) dst[i] = src[i];
    }
    for (int i = tid; i < ADIM * NBIL; i += 256) sWa[i] = a_sbf_w[i];
    __syncthreads();
    float ta[NBIL];
    #pragma unroll
    for (int j = 0; j < NBIL; ++j) ta[j] = 0.0f;
    const float* row = sA + tid * ADIM;
    #pragma unroll
    for (int k = 0; k < ADIM; ++k) {
        float v = row[k];
        #pragma unroll
        for (int j = 0; j < NBIL; ++j) ta[j] = fmaf(v, sWa[k * NBIL + j], ta[j]);
    }
    const int e = kj_idx[w0 + tid];
    float* dst = ta_sum + (size_t)e * NBIL;
    #pragma unroll
    for (int j = 0; j < NBIL; ++j) unsafeAtomicAdd(dst + j, ta[j]);
}

// ---------------------------------------------------------------------------
// fused edge kernel: 2 independent 64-edge tiles per block, 4 waves
// (col-split). Per stage both tiles' GEMMs run back-to-back on SHARED
// B-fragments, epilogues overlap the second tile's MFMAs. One barrier
// pair per stage serves both tiles.
// ---------------------------------------------------------------------------
__global__ __launch_bounds__(NTHR) void edge_main_k(
    const float* __restrict__ m_ji, const float* __restrict__ e_rbf,
    const float* __restrict__ ta_sum, const unsigned short* __restrict__ wt,
    const float* __restrict__ nbr_m_b, const float* __restrict__ e_rbf_w,
    const float* __restrict__ m_ji_b, const float* __restrict__ post_b,
    const float* __restrict__ res_b, float* __restrict__ out)
{
    __shared__ __align__(16) unsigned int sXdA[TP * TE * SXD]; // 34.8 KB act
    __shared__ __align__(16) unsigned int sTdA[TP * TE * SXD]; // 34.8 KB transf
    __shared__ __align__(16) float sTAT[NBIL * TP * TE];       // 4 KB
    __shared__ __align__(16) float sET[NRBF * TP * TE];        // 3 KB

    const int tid  = threadIdx.x;
    const int lane = tid & 63;
    const int ml   = lane & 15;
    const int g    = lane >> 4;
    const int wq   = tid >> 6;
    const int n0   = wq * 32;
    const int q16  = wq * 16;
    const size_t e0 = (size_t)blockIdx.x * (TP * TE);
    const int ET = TP * TE;                            // 128 edges per block

    bf16x8 A[4][2], Bf[2][4];
    f32x4 acc0[4][2], acc1[4][2], xr0[4][2], xr1[4][2], bs0, bs1;

    auto prefB = [&](const unsigned short* wtm, int ldk, int kbase) {
        #pragma unroll
        for (int nt = 0; nt < 2; ++nt) {
            const unsigned short* wb =
                wtm + (size_t)(n0 + nt * 16 + ml) * ldk + kbase + g * 8;
            #pragma unroll
            for (int ks = 0; ks < 4; ++ks)
                Bf[nt][ks] = *(const bf16x8*)(wb + ks * 32);
        }
    };
    auto ldbias = [&](const float* bp) {
        float b0 = bp[n0 + ml], b1 = bp[n0 + 16 + ml];
        bs0[0] = b0; bs0[1] = b0; bs0[2] = b0; bs0[3] = b0;
        bs1[0] = b1; bs1[1] = b1; bs1[2] = b1; bs1[3] = b1;
    };
    auto ldzero = [&]() {
        #pragma unroll
        for (int r = 0; r < 4; ++r) { bs0[r] = 0.f; bs1[r] = 0.f; }
    };

    prefB(wt + 1 * 16384, DIM, 0);                     // m_ji_w for S1

    // ---- prologue staging: 128 edges of m_ji packed, ta/e transposed
    #pragma unroll
    for (int i = 0; i < 8; ++i) {
        int q = tid + i * NTHR;                        // 2048 chunks of 4 dw
        int row = q >> 4, sub = q & 15;
        int dq = sub >> 2, c4 = (sub & 3) * 4;
        const float* src = m_ji + (e0 + row) * DIM + dq * 32 + c4;
        float4 a = *(const float4*)(src);
        float4 b = *(const float4*)(src + 16);
        uint4 d;
        d.x = pk2(a.x, b.x); d.y = pk2(a.y, b.y);
        d.z = pk2(a.z, b.z); d.w = pk2(a.w, b.w);
        *(uint4*)(sXdA + row * SXD + dq * 16 + c4) = d;   // rows 64.. land in tile1
    }
    #pragma unroll
    for (int i = 0; i < 4; ++i) {
        int idx = tid + i * NTHR;                      // 1024: j-major over 128 e
        int j = idx >> 7, e = idx & 127;
        sTAT[j * ET + e] = ta_sum[(e0 + e) * NBIL + j];
    }
    for (int i = tid; i < NRBF * ET; i += NTHR) {
        int j = i >> 7, e = i & 127;
        sET[j * ET + e] = e_rbf[(e0 + e) * NRBF + j];
    }
    __syncthreads();

    auto loadA = [&](const unsigned int* bufp, int h) {
        const unsigned short* base = (const unsigned short*)bufp;
        #pragma unroll
        for (int mt = 0; mt < 4; ++mt) {
            const unsigned short* rb = base + (mt * 16 + ml) * (SXD * 2) + h * 64 + g * 8;
            A[mt][0] = *(const bf16x8*)(rb);
            A[mt][1] = *(const bf16x8*)(rb + 32);
        }
    };
    auto mfmaH = [&](f32x4 (&acc)[4][2], int h, bool seed) {
        #pragma unroll
        for (int kk = 0; kk < 2; ++kk)
        #pragma unroll
        for (int nt = 0; nt < 2; ++nt)
        #pragma unroll
        for (int mt = 0; mt < 4; ++mt) {
            f32x4 cin = (seed && kk == 0) ? (nt == 0 ? bs0 : bs1) : acc[mt][nt];
            acc[mt][nt] = __builtin_amdgcn_mfma_f32_16x16x32_bf16(
                A[mt][kk], Bf[nt][h * 2 + kk], cin, 0, 0, 0);
        }
    };
    auto gemm_full = [&](const unsigned int* bufp, f32x4 (&acc)[4][2]) {
        loadA(bufp, 0); mfmaH(acc, 0, true); loadA(bufp, 1); mfmaH(acc, 1, false);
    };
    // both tiles' results -> act buffers, one barrier pair
    auto store_pair = [&](f32x4 (&v0)[4][2], f32x4 (&v1)[4][2]) {
        __syncthreads();
        #pragma unroll
        for (int mt = 0; mt < 4; ++mt)
        #pragma unroll
        for (int r = 0; r < 4; ++r) {
            int off = (mt * 16 + g * 4 + r) * SXD + q16 + ml;
            sXdA[off]               = pk2(v0[mt][0][r], v0[mt][1][r]);
            sXdA[TE * SXD + off]    = pk2(v1[mt][0][r], v1[mt][1][r]);
        }
        __syncthreads();
    };

    const unsigned int* b0p = sXdA;
    const unsigned int* b1p = sXdA + TE * SXD;

    // ---- S1: transf = silu(m_ji @ m_ji_w + b) -> sTd (lane-local)
    ldbias(m_ji_b);
    gemm_full(b0p, acc0);
    gemm_full(b1p, acc1);
    prefB(wt + 0 * 16384, DIM, 0);
    #pragma unroll
    for (int mt = 0; mt < 4; ++mt)
    #pragma unroll
    for (int r = 0; r < 4; ++r) {
        int off = (mt * 16 + g * 4 + r) * SXD + q16 + ml;
        sTdA[off]            = pk2(silu_f(acc0[mt][0][r]), silu_f(acc0[mt][1][r]));
        sTdA[TE * SXD + off] = pk2(silu_f(acc1[mt][0][r]), silu_f(acc1[mt][1][r]));
    }

    // ---- S2: me = silu(m_ji @ nbr_m_w + b) * (e_rbf @ e_rbf_w)
    ldbias(nbr_m_b);
    float ewc[2][NRBF];
    #pragma unroll
    for (int nt = 0; nt < 2; ++nt)
    #pragma unroll
    for (int q = 0; q < NRBF; ++q)
        ewc[nt][q] = e_rbf_w[q * DIM + n0 + nt * 16 + ml];
    gemm_full(b0p, acc0);
    gemm_full(b1p, acc1);
    const unsigned short* fwb = wt + 9 * 16384;
    prefB(fwb, NBIL * DIM, 0);
    #pragma unroll
    for (int t = 0; t < 2; ++t) {
        f32x4 (&ac)[4][2] = (t == 0) ? acc0 : acc1;
        #pragma unroll
        for (int mt = 0; mt < 4; ++mt) {
            f32x4 er[NRBF];
            #pragma unroll
            for (int q = 0; q < NRBF; ++q)
                er[q] = *(const f32x4*)(sET + q * ET + t * TE + mt * 16 + g * 4);
            #pragma unroll
            for (int r = 0; r < 4; ++r) {
                float te0 = 0.f, te1 = 0.f;
                #pragma unroll
                for (int q = 0; q < NRBF; ++q) {
                    te0 = fmaf(er[q][r], ewc[0][q], te0);
                    te1 = fmaf(er[q][r], ewc[1][q], te1);
                }
                ac[mt][0][r] = silu_f(ac[mt][0][r]) * te0;
                ac[mt][1][r] = silu_f(ac[mt][1][r]) * te1;
            }
        }
    }
    store_pair(acc0, acc1);                            // act = me

    // ---- S3 bilinear: xr = transf + sum_j ta_j * (me @ fw_j^T)
    #pragma unroll
    for (int mt = 0; mt < 4; ++mt)
    #pragma unroll
    for (int r = 0; r < 4; ++r) {
        int off = (mt * 16 + g * 4 + r) * SXD + q16 + ml;
        unsigned int t0 = sTdA[off], t1 = sTdA[TE * SXD + off];
        xr0[mt][0][r] = bf2f((unsigned short)(t0 & 0xffff));
        xr0[mt][1][r] = bf2f((unsigned short)(t0 >> 16));
        xr1[mt][0][r] = bf2f((unsigned short)(t1 & 0xffff));
        xr1[mt][1][r] = bf2f((unsigned short)(t1 >> 16));
    }
    ldzero();
    for (int j = 0; j < NBIL; ++j) {
        gemm_full(b0p, acc0);
        gemm_full(b1p, acc1);
        if (j < NBIL - 1) prefB(fwb, NBIL * DIM, (j + 1) * DIM);
        else              prefB(wt + 3 * 16384, DIM, 0);
        #pragma unroll
        for (int mt = 0; mt < 4; ++mt) {
            f32x4 tv0 = *(const f32x4*)(sTAT + j * ET + mt * 16 + g * 4);
            f32x4 tv1 = *(const f32x4*)(sTAT + j * ET + TE + mt * 16 + g * 4);
            #pragma unroll
            for (int nt = 0; nt < 2; ++nt)
            #pragma unroll
            for (int r = 0; r < 4; ++r) {
                xr0[mt][nt][r] = fmaf(tv0[r], acc0[mt][nt][r], xr0[mt][nt][r]);
                xr1[mt][nt][r] = fmaf(tv1[r], acc1[mt][nt][r], xr1[mt][nt][r]);
            }
        }
    }
    store_pair(xr0, xr1);                              // act = x

    // ---- generic residual-half + post stages
    auto silu_inplace = [&](f32x4 (&ac)[4][2]) {
        #pragma unroll
        for (int mt = 0; mt < 4; ++mt)
        #pragma unroll
        for (int r = 0; r < 4; ++r) {
            ac[mt][0][r] = silu_f(ac[mt][0][r]);
            ac[mt][1][r] = silu_f(ac[mt][1][r]);
        }
    };
    auto add_into = [&](f32x4 (&xr)[4][2], f32x4 (&ac)[4][2]) {
        #pragma unroll
        for (int mt = 0; mt < 4; ++mt)
        #pragma unroll
        for (int r = 0; r < 4; ++r) {
            xr[mt][0][r] += silu_f(ac[mt][0][r]);
            xr[mt][1][r] += silu_f(ac[mt][1][r]);
        }
    };

    // res0
    ldbias(res_b + 0);
    gemm_full(b0p, acc0); gemm_full(b1p, acc1); prefB(wt + 4 * 16384, DIM, 0);
    silu_inplace(acc0); silu_inplace(acc1);
    store_pair(acc0, acc1);                            // act = h
    ldbias(res_b + 128);
    gemm_full(b0p, acc0); gemm_full(b1p, acc1); prefB(wt + 2 * 16384, DIM, 0);
    add_into(xr0, acc0); add_into(xr1, acc1);
    store_pair(xr0, xr1);                              // act = x

    // post: x = silu(x @ post_w + b) + transf
    ldbias(post_b);
    gemm_full(b0p, acc0); gemm_full(b1p, acc1); prefB(wt + 5 * 16384, DIM, 0);
    #pragma unroll
    for (int mt = 0; mt < 4; ++mt)
    #pragma unroll
    for (int r = 0; r < 4; ++r) {
        int off = (mt * 16 + g * 4 + r) * SXD + q16 + ml;
        unsigned int t0 = sTdA[off], t1 = sTdA[TE * SXD + off];
        xr0[mt][0][r] = silu_f(acc0[mt][0][r]) + bf2f((unsigned short)(t0 & 0xffff));
        xr0[mt][1][r] = silu_f(acc0[mt][1][r]) + bf2f((unsigned short)(t0 >> 16));
        xr1[mt][0][r] = silu_f(acc1[mt][0][r]) + bf2f((unsigned short)(t1 & 0xffff));
        xr1[mt][1][r] = silu_f(acc1[mt][1][r]) + bf2f((unsigned short)(t1 >> 16));
    }
    store_pair(xr0, xr1);

    // res1
    ldbias(res_b + 256);
    gemm_full(b0p, acc0); gemm_full(b1p, acc1); prefB(wt + 6 * 16384, DIM, 0);
    silu_inplace(acc0); silu_inplace(acc1);
    store_pair(acc0, acc1);
    ldbias(res_b + 384);
    gemm_full(b0p, acc0); gemm_full(b1p, acc1); prefB(wt + 7 * 16384, DIM, 0);
    add_into(xr0, acc0); add_into(xr1, acc1);
    store_pair(xr0, xr1);

    // res2 + fused store
    ldbias(res_b + 512);
    gemm_full(b0p, acc0); gemm_full(b1p, acc1); prefB(wt + 8 * 16384, DIM, 0);
    silu_inplace(acc0); silu_inplace(acc1);
    store_pair(acc0, acc1);
    ldbias(res_b + 640);
    gemm_full(b0p, acc0); gemm_full(b1p, acc1);
    #pragma unroll
    for (int mt = 0; mt < 4; ++mt)
    #pragma unroll
    for (int r = 0; r < 4; ++r) {
        int row = mt * 16 + g * 4 + r;
        out[(e0 + row) * DIM + n0 + ml]           = silu_f(acc0[mt][0][r]) + xr0[mt][0][r];
        out[(e0 + row) * DIM + n0 + 16 + ml]      = silu_f(acc0[mt][1][r]) + xr0[mt][1][r];
        out[(e0 + TE + row) * DIM + n0 + ml]      = silu_f(acc1[mt][0][r]) + xr1[mt][0][r];
        out[(e0 + TE + row) * DIM + n0 + 16 + ml] = silu_f(acc1[mt][1][r]) + xr1[mt][1][r];
    }
}

// ---------------------------------------------------------------------------
extern "C" void kernel_launch(void* const* d_in, const int* in_sizes, int n_in,
                              void* d_out, int out_size, void* d_ws, size_t ws_size,
                              hipStream_t stream)
{
    (void)in_sizes; (void)n_in; (void)out_size;
    const float* m_ji    = (const float*)d_in[0];
    const float* e_rbf   = (const float*)d_in[1];
    const float* a_sbf   = (const float*)d_in[2];
    const int*   kj_idx  = (const int*)d_in[5];
    const float* nbr_m_w = (const float*)d_in[6];
    const float* nbr_m_b = (const float*)d_in[7];
    const float* e_rbf_w = (const float*)d_in[8];
    const float* a_sbf_w = (const float*)d_in[9];
    const float* final_w = (const float*)d_in[10];
    const float* m_ji_w  = (const float*)d_in[11];
    const float* m_ji_b  = (const float*)d_in[12];
    const float* post_w  = (const float*)d_in[13];
    const float* post_b  = (const float*)d_in[14];
    const float* res_w   = (const float*)d_in[15];
    const float* res_b   = (const float*)d_in[16];
    float* out = (float*)d_out;

    const size_t taB  = (size_t)N_EDGE * NBIL * sizeof(float);      // 8.4 MB
    const size_t wtB  = (size_t)278528 * sizeof(unsigned short);    // 0.56 MB
    const size_t tawB = (size_t)N_TRI * NBIL * sizeof(float);       // 33.6 MB

    float* ta_sum = (float*)d_ws;
    unsigned short* wt = (unsigned short*)((char*)d_ws + taB);
    float* taw = (float*)((char*)d_ws + taB + wtB);

    prep_w_k<<<1088, 256, 0, stream>>>(nbr_m_w, m_ji_w, post_w, res_w, final_w, wt);
    hipMemsetAsync(ta_sum, 0, taB, stream);

    if (ws_size >= taB + wtB + tawB) {
        ta_all_k<<<N_TRI / 256, 256, 0, stream>>>(a_sbf, a_sbf_w, taw);
        seg_reduce_k<<<(N_EDGE / EB2) * NSL, 1024, 0, stream>>>(taw, kj_idx, ta_sum);
    } else {
        triplet_atomic_k<<<N_TRI / 256, 256, 0, stream>>>(a_sbf, a_sbf_w, kj_idx, ta_sum);
    }
    edge_main_k<<<N_EDGE / (TP * TE), NTHR, 0, stream>>>(m_ji, e_rbf, ta_sum, wt,
        nbr_m_b, e_rbf_w, m_ji_b, post_b, res_b, out);
}